// Round 6
// baseline (41332.480 us; speedup 1.0000x reference)
//
#include <hip/hip_runtime.h>
#include <cstdint>

typedef __bf16 bf16;
typedef bf16 bf16x8 __attribute__((ext_vector_type(8)));
typedef bf16 bf16x4 __attribute__((ext_vector_type(4)));
typedef float f32x4 __attribute__((ext_vector_type(4)));

#define DI __device__ __forceinline__

DI float sigmoidf_(float x) { return 1.0f / (1.0f + __expf(-x)); }
DI float tanhf_(float x)    { return 1.0f - 2.0f / (__expf(2.0f * x) + 1.0f); }

// ---------------------------------------------------------------------------
// Grid-wide barrier v2. Key fix vs round 3/4: the spin loop uses RELAXED
// agent loads (no cache invalidate per iteration); exactly ONE acquire at
// exit and ONE release at arrival per block. bar[0]=count, bar[1]=gen.
// ---------------------------------------------------------------------------
DI void gsync(int* bar)
{
  __syncthreads();
  if (threadIdx.x == 0) {
    int gen = __hip_atomic_load(bar + 1, __ATOMIC_RELAXED, __HIP_MEMORY_SCOPE_AGENT);
    // RELEASE arrival: waitcnt + L2 writeback, then the fabric atomic.
    if (__hip_atomic_fetch_add(bar, 1, __ATOMIC_RELEASE, __HIP_MEMORY_SCOPE_AGENT)
        == (int)gridDim.x - 1) {
      __hip_atomic_store(bar, 0, __ATOMIC_RELAXED, __HIP_MEMORY_SCOPE_AGENT);
      __hip_atomic_store(bar + 1, gen + 1, __ATOMIC_RELEASE, __HIP_MEMORY_SCOPE_AGENT);
    } else {
      // RELAXED spin: no invalidates while waiting.
      while (__hip_atomic_load(bar + 1, __ATOMIC_RELAXED, __HIP_MEMORY_SCOPE_AGENT) == gen)
        __builtin_amdgcn_s_sleep(2);
    }
    // Single ACQUIRE: one L1/L2 invalidate so subsequent normal loads are fresh.
    (void)__hip_atomic_load(bar + 1, __ATOMIC_ACQUIRE, __HIP_MEMORY_SCOPE_AGENT);
  }
  __syncthreads();
}

// ---------------------------------------------------------------------------
// GEMM core, K=512 fully unrolled: C[n][b] += W[n][k]*act[b][k]
//   A-op (W): m=lane&15, k=(lane>>4)*8+j ; B-op (act): n=lane&15, same k
//   C/D: col(=b)=lane&15, row(=n)=(lane>>4)*4+reg
// ---------------------------------------------------------------------------
template<int NB>
DI void mm512(f32x4* acc, const bf16* __restrict__ wrow,
              const bf16* __restrict__ act, int q, int col)
{
#pragma unroll
  for (int ki = 0; ki < 16; ++ki) {
    const int k = ki * 32 + q * 8;
    bf16x8 wf = *(const bf16x8*)(wrow + k);
#pragma unroll
    for (int bt = 0; bt < NB; ++bt) {
      bf16x8 af = *(const bf16x8*)(act + (long)(bt * 16 + col) * 512 + k);
      acc[bt] = __builtin_amdgcn_mfma_f32_16x16x32_bf16(wf, af, acc[bt], 0, 0, 0);
    }
  }
}

// --------------------------- LSTM level (vb in [0,96)) ---------------------
// vb = bx(32) x ax(3), NB=8 (full batch). Wcat [a][l][n=4o+g][k 0:Wx|512:Wh].
DI void d_lstm(int vb, int tid,
               const bf16* __restrict__ A0, long a0ss,
               const bf16* __restrict__ A1,
               const bf16* __restrict__ W,
               const float* __restrict__ bias,
               const float* __restrict__ csR,
               float* __restrict__ csW,
               bf16* __restrict__ hOut)
{
  const int bx = vb & 31, ax = vb >> 5;
  const int lane = tid & 63, wave = tid >> 6;
  const int q = lane >> 4, col = lane & 15;
  const int n0 = bx * 64 + wave * 16;
  const bf16* wrow = W + (long)ax * 10485760L + (long)(n0 + col) * 1024;
  f32x4 acc[8] = {};
  mm512<8>(acc, wrow,       A0 + (long)ax * a0ss,  q, col);
  mm512<8>(acc, wrow + 512, A1 + (long)ax * 65536, q, col);
  const int o = (n0 >> 2) + q;
  const float* bi = bias + (long)ax * 10240;
  float b0f = bi[o], b1f = bi[512 + o], b2f = bi[1024 + o], b3f = bi[1536 + o];
  const float* csr = csR + (long)ax * 65536;
  float* csw = csW + (long)ax * 65536;
  bf16* hl = hOut + (long)ax * 65536;
#pragma unroll
  for (int bt = 0; bt < 8; ++bt) {
    int b = bt * 16 + col;
    float ig = sigmoidf_(acc[bt][0] + b0f);
    float fg = sigmoidf_(acc[bt][1] + b1f);
    float gg = tanhf_   (acc[bt][2] + b2f);
    float og = sigmoidf_(acc[bt][3] + b3f);
    long idx = (long)b * 512 + o;
    float cn = fg * csr[idx] + ig * gg;
    csw[idx] = cn;
    hl[idx] = (bf16)(og * tanhf_(cn));
  }
}

// --------------------------- cell_fn gates (vb in [0,480)) -----------------
// vb = bx(32) x sl(15), sl = l*3+a, NB=8. Wg [sl][n=4z+g][k 0:Wg_h|512:Wg_p].
DI void d_cell(int vb, int tid,
               const bf16* __restrict__ hg, const bf16* __restrict__ hsC,
               const bf16* __restrict__ Wg, const float* __restrict__ bgp,
               const float* __restrict__ csC,
               bf16* __restrict__ icat, bf16* __restrict__ ccat)
{
  const int bx = vb & 31, sl = vb >> 5;
  const int l = sl / 3, a = sl - l * 3;
  const int lane = tid & 63, wave = tid >> 6;
  const int q = lane >> 4, col = lane & 15;
  const int n0 = bx * 64 + wave * 16;
  const bf16* wrow = Wg + (long)sl * 2097152L + (long)(n0 + col) * 1024;
  f32x4 acc[8] = {};
  mm512<8>(acc, wrow,       hg,                     q, col);
  mm512<8>(acc, wrow + 512, hsC + (long)sl * 65536, q, col);
  const int z = (n0 >> 2) + q;
  const float* bgl = bgp + (long)sl * 1536;
  float g0 = bgl[z], g1 = bgl[512 + z], g2 = bgl[1024 + z];
  const float* csl = csC + (long)sl * 65536;
  const long obase = (long)l * 196608 + (long)a * 512 + z;
#pragma unroll
  for (int bt = 0; bt < 8; ++bt) {
    int b = bt * 16 + col;
    float ig = sigmoidf_(acc[bt][0] + g0);
    float fg = sigmoidf_(acc[bt][1] + g1);
    float gg = tanhf_   (acc[bt][2] + g2);
    float sc = csl[(long)b * 512 + z];
    float icl = ig * sc;
    float ccl = fg * gg + icl;
    long oi = obase + (long)b * 1536;
    icat[oi] = (bf16)icl;
    ccat[oi] = (bf16)ccl;
  }
}

// ----------------------- t1/t2 dual GEMM (vb in [0,80)) --------------------
// vb = bx(8) x by(2) x l(5), NB=4 dual, K=1536. Wt [l][y][k=a*512+z].
DI void d_tg(int vb, int tid,
             const bf16* __restrict__ icat, const bf16* __restrict__ ccat,
             const bf16* __restrict__ Wt, const float* __restrict__ bilc,
             float* __restrict__ t1s, float* __restrict__ t2s)
{
  const int bx = vb & 7, by = (vb >> 3) & 1, l = vb >> 4;
  const int lane = tid & 63, wave = tid >> 6;
  const int q = lane >> 4, col = lane & 15;
  const int n0 = bx * 64 + wave * 16;
  const int b0 = by * 64;
  const bf16* wp = Wt + (long)l * 786432L + (long)(n0 + col) * 1536 + q * 8;
  const bf16* ic = icat + (long)l * 196608 + (long)b0 * 1536 + q * 8;
  const bf16* cc = ccat + (long)l * 196608 + (long)b0 * 1536 + q * 8;
  f32x4 a1[4] = {}, a2[4] = {};
#pragma unroll 8
  for (int ki = 0; ki < 48; ++ki) {
    const long k = (long)ki * 32;
    bf16x8 wf = *(const bf16x8*)(wp + k);
#pragma unroll
    for (int bt = 0; bt < 4; ++bt) {
      long ro = (long)(bt * 16 + col) * 1536 + k;
      bf16x8 f1 = *(const bf16x8*)(ic + ro);
      bf16x8 f2 = *(const bf16x8*)(cc + ro);
      a1[bt] = __builtin_amdgcn_mfma_f32_16x16x32_bf16(wf, f1, a1[bt], 0, 0, 0);
      a2[bt] = __builtin_amdgcn_mfma_f32_16x16x32_bf16(wf, f2, a2[bt], 0, 0, 0);
    }
  }
  const int yb = n0 + 4 * q;
  const float* bl = bilc + (long)l * 1536;
  f32x4 bs;
#pragma unroll
  for (int r = 0; r < 4; ++r) bs[r] = bl[yb + r] + bl[512 + yb + r] + bl[1024 + yb + r];
#pragma unroll
  for (int bt = 0; bt < 4; ++bt) {
    int b = b0 + bt * 16 + col;
    f32x4 v1 = a1[bt] + bs, v2 = a2[bt] + bs;
    *(f32x4*)(t1s + ((long)l * 128 + b) * 512 + yb) = v1;
    *(f32x4*)(t2s + ((long)l * 128 + b) * 512 + yb) = v2;
  }
}

// ------------------ softmax/sigmoid combine (vb in [0,40)) -----------------
// vb = bgrp(8) x l(5); wave handles 4 b-rows of 512.
DI void d_comb(int vb, int tid,
               const float* __restrict__ t1s, const float* __restrict__ t2s,
               bf16* __restrict__ cat)
{
  const int bgrp = vb & 7, l = vb >> 3;
  const int lane = tid & 63, wave = tid >> 6;
#pragma unroll
  for (int i = 0; i < 4; ++i) {
    const int b = bgrp * 16 + wave * 4 + i;
    const float* r1 = t1s + ((long)l * 128 + b) * 512 + lane * 8;
    const float* r2 = t2s + ((long)l * 128 + b) * 512 + lane * 8;
    f32x4 u0 = *(const f32x4*)r1, u1 = *(const f32x4*)(r1 + 4);
    float mx = u0[0];
#pragma unroll
    for (int j = 1; j < 4; ++j) mx = fmaxf(mx, u0[j]);
#pragma unroll
    for (int j = 0; j < 4; ++j) mx = fmaxf(mx, u1[j]);
    for (int d = 32; d > 0; d >>= 1) mx = fmaxf(mx, __shfl_xor(mx, d, 64));
    float e[8], ss = 0.f;
#pragma unroll
    for (int j = 0; j < 4; ++j) { e[j] = __expf(u0[j] - mx); ss += e[j]; }
#pragma unroll
    for (int j = 0; j < 4; ++j) { e[4 + j] = __expf(u1[j] - mx); ss += e[4 + j]; }
    for (int d = 32; d > 0; d >>= 1) ss += __shfl_xor(ss, d, 64);
    float inv = 1.0f / ss;
    f32x4 w0 = *(const f32x4*)r2, w1 = *(const f32x4*)(r2 + 4);
    bf16x8 ob;
#pragma unroll
    for (int j = 0; j < 4; ++j) ob[j]     = (bf16)(sigmoidf_(w0[j]) * e[j]     * inv);
#pragma unroll
    for (int j = 0; j < 4; ++j) ob[4 + j] = (bf16)(sigmoidf_(w1[j]) * e[4 + j] * inv);
    *(bf16x8*)(cat + (long)b * 2560 + l * 512 + lane * 8) = ob;
  }
}

// ------------- single_li + per-step linear, fused (vb in [0,8)) ------------
// Block covers 16 batch rows. Wave w: n-half (w&1), K-half (w>>1); acc via LDS.
DI void d_slgfin(int vb, int tid,
                 const bf16* __restrict__ cat, const bf16* __restrict__ Wsl,
                 const float* __restrict__ bsl, const float* __restrict__ wlin,
                 const float* __restrict__ blin,
                 bf16* __restrict__ hg, float* __restrict__ out, int tc,
                 float* __restrict__ lds)
{
  const int lane = tid & 63, wave = tid >> 6;
  const int q = lane >> 4, col = lane & 15;
  const int b0 = vb * 16;
  const int nh = wave & 1, kh = wave >> 1;
  const bf16* arow  = cat + (long)(b0 + col) * 2560 + kh * 1280 + q * 8;
  const bf16* wbase = Wsl + (long)(nh * 256 + col) * 2560 + kh * 1280 + q * 8;
  f32x4 acc[16] = {};
#pragma unroll 2
  for (int ki = 0; ki < 40; ++ki) {
    const long k = ki * 32;
    bf16x8 af = *(const bf16x8*)(arow + k);
#pragma unroll
    for (int j = 0; j < 16; ++j) {
      bf16x8 wf = *(const bf16x8*)(wbase + (long)j * 40960 + k);
      acc[j] = __builtin_amdgcn_mfma_f32_16x16x32_bf16(wf, af, acc[j], 0, 0, 0);
    }
  }
#pragma unroll
  for (int j = 0; j < 16; ++j) {
    int n = nh * 256 + j * 16 + q * 4;
    *(f32x4*)(lds + (kh * 16 + col) * 516 + n) = acc[j];
  }
  __syncthreads();
#pragma unroll
  for (int i = 0; i < 4; ++i) {
    const int bi = wave * 4 + i;
    const int n0 = lane * 8;
    const float* p0 = lds + bi * 516 + n0;
    const float* p1 = lds + (16 + bi) * 516 + n0;
    f32x4 s0 = *(const f32x4*)p0 + *(const f32x4*)p1 + *(const f32x4*)(bsl + n0);
    f32x4 s1 = *(const f32x4*)(p0 + 4) + *(const f32x4*)(p1 + 4)
             + *(const f32x4*)(bsl + n0 + 4);
    bf16x8 hb;
#pragma unroll
    for (int j = 0; j < 4; ++j) { hb[j] = (bf16)s0[j]; hb[4 + j] = (bf16)s1[j]; }
    *(bf16x8*)(hg + (long)(b0 + bi) * 512 + n0) = hb;
    const float* wl = wlin + (long)tc * 512 + n0;
    f32x4 w0 = *(const f32x4*)wl, w1 = *(const f32x4*)(wl + 4);
    float dot = s0[0]*w0[0] + s0[1]*w0[1] + s0[2]*w0[2] + s0[3]*w0[3]
              + s1[0]*w1[0] + s1[1]*w1[1] + s1[2]*w1[2] + s1[3]*w1[3];
    for (int d = 32; d > 0; d >>= 1) dot += __shfl_xor(dot, d, 64);
    if (lane == 0) out[tc * 128 + (b0 + bi)] = dot + blin[tc];
  }
}

// ------------------------- persistent pipelined kernel ---------------------
// grid 512 x 256thr = 2 blocks/CU guaranteed co-resident
// (LDS 66KB*2 <= 160KB, VGPR <= 256). 8 waves/CU.
__global__ __launch_bounds__(256, 2) void k_persist(
    const bf16* __restrict__ xbf, const bf16* __restrict__ Wcat,
    const float* __restrict__ b_l, const bf16* __restrict__ Wg,
    const float* __restrict__ bg, const bf16* __restrict__ Wt,
    const float* __restrict__ bilc, const bf16* __restrict__ Wslb,
    const float* __restrict__ bsl, const float* __restrict__ Wlin,
    const float* __restrict__ blin,
    bf16* hs0, bf16* hs1, bf16* hgb, float* cs0, float* cs1,
    bf16* icat, bf16* ccat, float* t1s, float* t2s, bf16* catb,
    float* out, int* bar)
{
  __shared__ float lds[16512];   // 66KB: slg+fin accumulator exchange
  const int tid = threadIdx.x;
  for (int s = 0; s < 65; ++s) {
    const bool doL = s < 64, doC = s > 0;
    const int t = doL ? s : 63, tc = doC ? s - 1 : 0;
    const bf16*  hsR = (t & 1) ? hs1 : hs0;
    bf16*        hsW = (t & 1) ? hs0 : hs1;
    const float* csR = (t & 1) ? cs1 : cs0;
    float*       csW = (t & 1) ? cs0 : cs1;
    const bf16*  hsC = (tc & 1) ? hs0 : hs1;
    const float* csC = (tc & 1) ? cs0 : cs1;
    for (int sl = 0; sl < 5; ++sl) {
      const int nL = doL ? 96 : 0;
      const int nC = doC ? ((sl < 2) ? 240 : (sl == 2) ? 80 : (sl == 3) ? 40 : 8) : 0;
      const bf16* A0 = (sl == 0) ? xbf + (long)t * 65536
                                 : hsW + (long)(sl - 1) * 196608;
      const long a0ss = (sl == 0) ? 0L : 65536L;
      for (int vb = blockIdx.x; vb < nL + nC; vb += (int)gridDim.x) {
        if (vb < nL) {
          d_lstm(vb, tid, A0, a0ss, hsR + (long)sl * 196608,
                 Wcat + (long)sl * 2097152, b_l + sl * 2048,
                 csR + (long)sl * 196608, csW + (long)sl * 196608,
                 hsW + (long)sl * 196608);
        } else {
          const int cv = vb - nL;
          if (sl == 0)      d_cell(cv,       tid, hgb, hsC, Wg, bg, csC, icat, ccat);
          else if (sl == 1) d_cell(cv + 240, tid, hgb, hsC, Wg, bg, csC, icat, ccat);
          else if (sl == 2) d_tg  (cv, tid, icat, ccat, Wt, bilc, t1s, t2s);
          else if (sl == 3) d_comb(cv, tid, t1s, t2s, catb);
          else d_slgfin(cv, tid, catb, Wslb, bsl, Wlin, blin, hgb, out, tc, lds);
        }
      }
      gsync(bar);
    }
  }
}

// ------------------------- weight conversion kernels -----------------------
__global__ __launch_bounds__(256) void cvt_wxh(const float* __restrict__ Wx,
    const float* __restrict__ Wh, bf16* __restrict__ dst)
{
  long idx = ((long)blockIdx.x * 256 + threadIdx.x) * 4;   // [al][n][k], n=4o+g
  int k = (int)(idx & 1023);
  int n = (int)((idx >> 10) & 2047);
  long al = idx >> 21;                                     // a*5+l
  int g = n & 3, o = n >> 2;
  const float* src = (k < 512)
      ? Wx + ((al * 4 + g) * 512 + o) * 512 + k
      : Wh + ((al * 4 + g) * 512 + o) * 512 + (k - 512);
  f32x4 v = *(const f32x4*)src;
  bf16x4 ov;
#pragma unroll
  for (int j = 0; j < 4; ++j) ov[j] = (bf16)v[j];
  *(bf16x4*)(dst + idx) = ov;
}

__global__ __launch_bounds__(256) void cvt_wg(const float* __restrict__ Wg_h,
    const float* __restrict__ Wg_p, bf16* __restrict__ dst)
{
  long idx = ((long)blockIdx.x * 256 + threadIdx.x) * 4;   // [la][n=4z+g][k], g==3 pad
  int k = (int)(idx & 1023);
  int n = (int)((idx >> 10) & 2047);
  long la = idx >> 21;                                     // l*3+a
  int g = n & 3, z = n >> 2;
  f32x4 v = {0, 0, 0, 0};
  if (g < 3) {
    const float* src = (k < 512)
        ? Wg_h + ((la * 3 + g) * 512 + z) * 512 + k
        : Wg_p + ((la * 3 + g) * 512 + z) * 512 + (k - 512);
    v = *(const f32x4*)src;
  }
  bf16x4 ov;
#pragma unroll
  for (int j = 0; j < 4; ++j) ov[j] = (bf16)v[j];
  *(bf16x4*)(dst + idx) = ov;
}

__global__ __launch_bounds__(256) void cvt_wt(const float* __restrict__ Wilc,
                                              bf16* __restrict__ dst)
{
  long idx = (long)blockIdx.x * 256 + threadIdx.x;         // [l][y][k=a*512+z]
  int k = (int)(idx % 1536);
  long rest = idx / 1536;
  int y = (int)(rest & 511);
  int l = (int)(rest >> 9);
  int a = k >> 9, z = k & 511;
  dst[idx] = (bf16)Wilc[(((long)l * 3 + a) * 512 + z) * 512 + y];
}

__global__ __launch_bounds__(256) void k_cast(const float* __restrict__ s,
                                              bf16* __restrict__ d)
{
  long i = ((long)blockIdx.x * 256 + threadIdx.x) * 4;
  f32x4 v = *(const f32x4*)(s + i);
  bf16x4 ov;
#pragma unroll
  for (int j = 0; j < 4; ++j) ov[j] = (bf16)v[j];
  *(bf16x4*)(d + i) = ov;
}

__global__ __launch_bounds__(256) void k_zero(uint4* __restrict__ p, long n)
{
  long i = (long)blockIdx.x * 256 + threadIdx.x;
  if (i < n) p[i] = make_uint4(0, 0, 0, 0);
}

// ---------------------------------------------------------------------------
extern "C" void kernel_launch(void* const* d_in, const int* in_sizes, int n_in,
                              void* d_out, int out_size, void* d_ws, size_t ws_size,
                              hipStream_t stream)
{
  const float* x    = (const float*)d_in[0];
  const float* Wx   = (const float*)d_in[1];
  const float* Wh   = (const float*)d_in[2];
  const float* b_l  = (const float*)d_in[3];
  const float* Wg_h = (const float*)d_in[4];
  const float* Wg_p = (const float*)d_in[5];
  const float* bg   = (const float*)d_in[6];
  const float* Wilc = (const float*)d_in[7];
  const float* bilc = (const float*)d_in[8];
  const float* Wsl  = (const float*)d_in[9];
  const float* bsl  = (const float*)d_in[10];
  const float* Wlin = (const float*)d_in[11];
  const float* blin = (const float*)d_in[12];
  float* out = (float*)d_out;

  char* w = (char*)d_ws;
  auto alloc = [&](long bytes) { char* p = w; w += (bytes + 255) & ~255L; return p; };
  bf16* Wcat = (bf16*)alloc(31457280L * 2);   // [a][l][2048][1024]
  bf16* Wg   = (bf16*)alloc(31457280L * 2);   // [l*3+a][2048][1024]
  bf16* Wt   = (bf16*)alloc(3932160L * 2);    // [l][512][1536]
  bf16* Wslb = (bf16*)alloc(1310720L * 2);    // [512][2560]
  bf16* xbf  = (bf16*)alloc(4194304L * 2);    // [t][b][512]
  char* zbase = w;
  bf16* hs0  = (bf16*)alloc(983040L * 2);     // [l][a][b][512] ping
  bf16* hs1  = (bf16*)alloc(983040L * 2);     // pong
  bf16* hgb  = (bf16*)alloc(65536L * 2);      // [b][512]
  float* cs0 = (float*)alloc(983040L * 4);    // [l][a][b][512] ping
  float* cs1 = (float*)alloc(983040L * 4);    // pong
  int*  bar  = (int*)alloc(256);              // grid barrier {count, gen}
  long zbytes = w - zbase;
  bf16* icat = (bf16*)alloc(983040L * 2);     // [l][b][1536]
  bf16* ccat = (bf16*)alloc(983040L * 2);
  float* t1s = (float*)alloc(327680L * 4);    // [l][b][512]
  float* t2s = (float*)alloc(327680L * 4);
  bf16* catb = (bf16*)alloc(327680L * 2);     // [b][2560]
  (void)ws_size; (void)n_in; (void)in_sizes; (void)out_size;

  // --- setup (runs every call; ws is re-poisoned by the harness) ---
  cvt_wxh<<<30720, 256, 0, stream>>>(Wx, Wh, Wcat);
  cvt_wg <<<30720, 256, 0, stream>>>(Wg_h, Wg_p, Wg);
  cvt_wt <<<15360, 256, 0, stream>>>(Wilc, Wt);
  k_cast <<<1280,  256, 0, stream>>>(Wsl, Wslb);
  k_cast <<<4096,  256, 0, stream>>>(x, xbf);
  {
    long n16 = zbytes / 16;
    k_zero<<<(int)((n16 + 255) / 256), 256, 0, stream>>>((uint4*)zbase, n16);
  }

  // --- one persistent kernel runs the whole 64-step recurrence ---
  k_persist<<<512, 256, 0, stream>>>(
      xbf, Wcat, b_l, Wg, bg, Wt, bilc, Wslb, bsl, Wlin, blin,
      hs0, hs1, hgb, cs0, cs1, icat, ccat, t1s, t2s, catb, out, bar);
}

// Round 7
// 33455.240 us; speedup vs baseline: 1.2355x; 1.2355x over previous
//
#include <hip/hip_runtime.h>
#include <cstdint>

typedef __bf16 bf16;
typedef bf16 bf16x8 __attribute__((ext_vector_type(8)));
typedef bf16 bf16x4 __attribute__((ext_vector_type(4)));
typedef float f32x4 __attribute__((ext_vector_type(4)));

#define DI __device__ __forceinline__

DI float sigmoidf_(float x) { return 1.0f / (1.0f + __expf(-x)); }
DI float tanhf_(float x)    { return 1.0f - 2.0f / (__expf(2.0f * x) + 1.0f); }

// ---------------------------------------------------------------------------
// Grid-wide barrier v3 — hierarchical, low-contention.
//  - 8 group arrival counters (one cacheline each): <=42 RMWs per line.
//  - root counter: 8 RMWs.
//  - 8 per-group generation lines; spinners poll ONLY their line with
//    s_sleep(32) (~2048 cyc) -> ~1 req / 48 cyc / line instead of 4/cyc.
//  - arrivals RELEASE (one wbl2/block), ONE acquire at exit (one inv/block).
// Layout (ints): gc[g]=g*32, root=256, gen[g]=288+g*32.
// ---------------------------------------------------------------------------
DI void gsync(int* bar, int nblk)
{
  __syncthreads();
  if (threadIdx.x == 0) {
    const int g = blockIdx.x & 7;
    int* gc   = bar + g * 32;
    int* root = bar + 8 * 32;
    int* gen  = bar + 9 * 32 + g * 32;
    const int gsz = nblk >> 3;
    int myg = __hip_atomic_load(gen, __ATOMIC_RELAXED, __HIP_MEMORY_SCOPE_AGENT);
    if (__hip_atomic_fetch_add(gc, 1, __ATOMIC_RELEASE, __HIP_MEMORY_SCOPE_AGENT)
        == gsz - 1) {
      if (__hip_atomic_fetch_add(root, 1, __ATOMIC_RELAXED, __HIP_MEMORY_SCOPE_AGENT)
          == 7) {
        __hip_atomic_store(root, 0, __ATOMIC_RELAXED, __HIP_MEMORY_SCOPE_AGENT);
#pragma unroll
        for (int j = 0; j < 8; ++j)
          __hip_atomic_store(bar + j * 32, 0, __ATOMIC_RELAXED, __HIP_MEMORY_SCOPE_AGENT);
#pragma unroll
        for (int j = 0; j < 8; ++j)
          __hip_atomic_store(bar + 9 * 32 + j * 32, myg + 1, __ATOMIC_RELEASE,
                             __HIP_MEMORY_SCOPE_AGENT);
      }
    }
    if (__hip_atomic_load(gen, __ATOMIC_RELAXED, __HIP_MEMORY_SCOPE_AGENT) == myg) {
      do { __builtin_amdgcn_s_sleep(32); }
      while (__hip_atomic_load(gen, __ATOMIC_RELAXED, __HIP_MEMORY_SCOPE_AGENT) == myg);
    }
    (void)__hip_atomic_load(gen, __ATOMIC_ACQUIRE, __HIP_MEMORY_SCOPE_AGENT);
  }
  __syncthreads();
}

// ---------------------------------------------------------------------------
// GEMM core, K=512 fully unrolled: C[n][b] += W[n][k]*act[b][k]
//   A-op (W): m=lane&15, k=(lane>>4)*8+j ; B-op (act): n=lane&15, same k
//   C/D: col(=b)=lane&15, row(=n)=(lane>>4)*4+reg
// ---------------------------------------------------------------------------
template<int NB>
DI void mm512(f32x4* acc, const bf16* __restrict__ wrow,
              const bf16* __restrict__ act, int q, int col)
{
#pragma unroll
  for (int ki = 0; ki < 16; ++ki) {
    const int k = ki * 32 + q * 8;
    bf16x8 wf = *(const bf16x8*)(wrow + k);
#pragma unroll
    for (int bt = 0; bt < NB; ++bt) {
      bf16x8 af = *(const bf16x8*)(act + (long)(bt * 16 + col) * 512 + k);
      acc[bt] = __builtin_amdgcn_mfma_f32_16x16x32_bf16(wf, af, acc[bt], 0, 0, 0);
    }
  }
}

// --------------------------- LSTM level (vb in [0,96)) ---------------------
// vb = bx(32) x ax(3), NB=8 (full batch). Wcat [a][l][n=4o+g][k 0:Wx|512:Wh].
DI void d_lstm(int vb, int tid,
               const bf16* __restrict__ A0, long a0ss,
               const bf16* __restrict__ A1,
               const bf16* __restrict__ W,
               const float* __restrict__ bias,
               const float* __restrict__ csR,
               float* __restrict__ csW,
               bf16* __restrict__ hOut)
{
  const int bx = vb & 31, ax = vb >> 5;
  const int lane = tid & 63, wave = tid >> 6;
  const int q = lane >> 4, col = lane & 15;
  const int n0 = bx * 64 + wave * 16;
  const bf16* wrow = W + (long)ax * 10485760L + (long)(n0 + col) * 1024;
  f32x4 acc[8] = {};
  mm512<8>(acc, wrow,       A0 + (long)ax * a0ss,  q, col);
  mm512<8>(acc, wrow + 512, A1 + (long)ax * 65536, q, col);
  const int o = (n0 >> 2) + q;
  const float* bi = bias + (long)ax * 10240;
  float b0f = bi[o], b1f = bi[512 + o], b2f = bi[1024 + o], b3f = bi[1536 + o];
  const float* csr = csR + (long)ax * 65536;
  float* csw = csW + (long)ax * 65536;
  bf16* hl = hOut + (long)ax * 65536;
#pragma unroll
  for (int bt = 0; bt < 8; ++bt) {
    int b = bt * 16 + col;
    float ig = sigmoidf_(acc[bt][0] + b0f);
    float fg = sigmoidf_(acc[bt][1] + b1f);
    float gg = tanhf_   (acc[bt][2] + b2f);
    float og = sigmoidf_(acc[bt][3] + b3f);
    long idx = (long)b * 512 + o;
    float cn = fg * csr[idx] + ig * gg;
    csw[idx] = cn;
    hl[idx] = (bf16)(og * tanhf_(cn));
  }
}

// --------------------------- cell_fn gates (vb in [0,480)) -----------------
// vb = bx(32) x sl(15), sl = l*3+a, NB=8. Wg [sl][n=4z+g][k 0:Wg_h|512:Wg_p].
DI void d_cell(int vb, int tid,
               const bf16* __restrict__ hg, const bf16* __restrict__ hsC,
               const bf16* __restrict__ Wg, const float* __restrict__ bgp,
               const float* __restrict__ csC,
               bf16* __restrict__ icat, bf16* __restrict__ ccat)
{
  const int bx = vb & 31, sl = vb >> 5;
  const int l = sl / 3, a = sl - l * 3;
  const int lane = tid & 63, wave = tid >> 6;
  const int q = lane >> 4, col = lane & 15;
  const int n0 = bx * 64 + wave * 16;
  const bf16* wrow = Wg + (long)sl * 2097152L + (long)(n0 + col) * 1024;
  f32x4 acc[8] = {};
  mm512<8>(acc, wrow,       hg,                     q, col);
  mm512<8>(acc, wrow + 512, hsC + (long)sl * 65536, q, col);
  const int z = (n0 >> 2) + q;
  const float* bgl = bgp + (long)sl * 1536;
  float g0 = bgl[z], g1 = bgl[512 + z], g2 = bgl[1024 + z];
  const float* csl = csC + (long)sl * 65536;
  const long obase = (long)l * 196608 + (long)a * 512 + z;
#pragma unroll
  for (int bt = 0; bt < 8; ++bt) {
    int b = bt * 16 + col;
    float ig = sigmoidf_(acc[bt][0] + g0);
    float fg = sigmoidf_(acc[bt][1] + g1);
    float gg = tanhf_   (acc[bt][2] + g2);
    float sc = csl[(long)b * 512 + z];
    float icl = ig * sc;
    float ccl = fg * gg + icl;
    long oi = obase + (long)b * 1536;
    icat[oi] = (bf16)icl;
    ccat[oi] = (bf16)ccl;
  }
}

// ----------------------- t1/t2 dual GEMM (vb in [0,80)) --------------------
// vb = bx(8) x by(2) x l(5), NB=4 dual, K=1536. Wt [l][y][k=a*512+z].
DI void d_tg(int vb, int tid,
             const bf16* __restrict__ icat, const bf16* __restrict__ ccat,
             const bf16* __restrict__ Wt, const float* __restrict__ bilc,
             float* __restrict__ t1s, float* __restrict__ t2s)
{
  const int bx = vb & 7, by = (vb >> 3) & 1, l = vb >> 4;
  const int lane = tid & 63, wave = tid >> 6;
  const int q = lane >> 4, col = lane & 15;
  const int n0 = bx * 64 + wave * 16;
  const int b0 = by * 64;
  const bf16* wp = Wt + (long)l * 786432L + (long)(n0 + col) * 1536 + q * 8;
  const bf16* ic = icat + (long)l * 196608 + (long)b0 * 1536 + q * 8;
  const bf16* cc = ccat + (long)l * 196608 + (long)b0 * 1536 + q * 8;
  f32x4 a1[4] = {}, a2[4] = {};
#pragma unroll 8
  for (int ki = 0; ki < 48; ++ki) {
    const long k = (long)ki * 32;
    bf16x8 wf = *(const bf16x8*)(wp + k);
#pragma unroll
    for (int bt = 0; bt < 4; ++bt) {
      long ro = (long)(bt * 16 + col) * 1536 + k;
      bf16x8 f1 = *(const bf16x8*)(ic + ro);
      bf16x8 f2 = *(const bf16x8*)(cc + ro);
      a1[bt] = __builtin_amdgcn_mfma_f32_16x16x32_bf16(wf, f1, a1[bt], 0, 0, 0);
      a2[bt] = __builtin_amdgcn_mfma_f32_16x16x32_bf16(wf, f2, a2[bt], 0, 0, 0);
    }
  }
  const int yb = n0 + 4 * q;
  const float* bl = bilc + (long)l * 1536;
  f32x4 bs;
#pragma unroll
  for (int r = 0; r < 4; ++r) bs[r] = bl[yb + r] + bl[512 + yb + r] + bl[1024 + yb + r];
#pragma unroll
  for (int bt = 0; bt < 4; ++bt) {
    int b = b0 + bt * 16 + col;
    f32x4 v1 = a1[bt] + bs, v2 = a2[bt] + bs;
    *(f32x4*)(t1s + ((long)l * 128 + b) * 512 + yb) = v1;
    *(f32x4*)(t2s + ((long)l * 128 + b) * 512 + yb) = v2;
  }
}

// ------------------ softmax/sigmoid combine (vb in [0,40)) -----------------
// vb = bgrp(8) x l(5); wave handles 4 b-rows of 512.
DI void d_comb(int vb, int tid,
               const float* __restrict__ t1s, const float* __restrict__ t2s,
               bf16* __restrict__ cat)
{
  const int bgrp = vb & 7, l = vb >> 3;
  const int lane = tid & 63, wave = tid >> 6;
#pragma unroll
  for (int i = 0; i < 4; ++i) {
    const int b = bgrp * 16 + wave * 4 + i;
    const float* r1 = t1s + ((long)l * 128 + b) * 512 + lane * 8;
    const float* r2 = t2s + ((long)l * 128 + b) * 512 + lane * 8;
    f32x4 u0 = *(const f32x4*)r1, u1 = *(const f32x4*)(r1 + 4);
    float mx = u0[0];
#pragma unroll
    for (int j = 1; j < 4; ++j) mx = fmaxf(mx, u0[j]);
#pragma unroll
    for (int j = 0; j < 4; ++j) mx = fmaxf(mx, u1[j]);
    for (int d = 32; d > 0; d >>= 1) mx = fmaxf(mx, __shfl_xor(mx, d, 64));
    float e[8], ss = 0.f;
#pragma unroll
    for (int j = 0; j < 4; ++j) { e[j] = __expf(u0[j] - mx); ss += e[j]; }
#pragma unroll
    for (int j = 0; j < 4; ++j) { e[4 + j] = __expf(u1[j] - mx); ss += e[4 + j]; }
    for (int d = 32; d > 0; d >>= 1) ss += __shfl_xor(ss, d, 64);
    float inv = 1.0f / ss;
    f32x4 w0 = *(const f32x4*)r2, w1 = *(const f32x4*)(r2 + 4);
    bf16x8 ob;
#pragma unroll
    for (int j = 0; j < 4; ++j) ob[j]     = (bf16)(sigmoidf_(w0[j]) * e[j]     * inv);
#pragma unroll
    for (int j = 0; j < 4; ++j) ob[4 + j] = (bf16)(sigmoidf_(w1[j]) * e[4 + j] * inv);
    *(bf16x8*)(cat + (long)b * 2560 + l * 512 + lane * 8) = ob;
  }
}

// ------------- single_li + per-step linear, fused (vb in [0,8)) ------------
// Block covers 16 batch rows. Wave w: n-half (w&1), K-half (w>>1); acc via LDS.
DI void d_slgfin(int vb, int tid,
                 const bf16* __restrict__ cat, const bf16* __restrict__ Wsl,
                 const float* __restrict__ bsl, const float* __restrict__ wlin,
                 const float* __restrict__ blin,
                 bf16* __restrict__ hg, float* __restrict__ out, int tc,
                 float* __restrict__ lds)
{
  const int lane = tid & 63, wave = tid >> 6;
  const int q = lane >> 4, col = lane & 15;
  const int b0 = vb * 16;
  const int nh = wave & 1, kh = wave >> 1;
  const bf16* arow  = cat + (long)(b0 + col) * 2560 + kh * 1280 + q * 8;
  const bf16* wbase = Wsl + (long)(nh * 256 + col) * 2560 + kh * 1280 + q * 8;
  f32x4 acc[16] = {};
#pragma unroll 2
  for (int ki = 0; ki < 40; ++ki) {
    const long k = ki * 32;
    bf16x8 af = *(const bf16x8*)(arow + k);
#pragma unroll
    for (int j = 0; j < 16; ++j) {
      bf16x8 wf = *(const bf16x8*)(wbase + (long)j * 40960 + k);
      acc[j] = __builtin_amdgcn_mfma_f32_16x16x32_bf16(wf, af, acc[j], 0, 0, 0);
    }
  }
#pragma unroll
  for (int j = 0; j < 16; ++j) {
    int n = nh * 256 + j * 16 + q * 4;
    *(f32x4*)(lds + (kh * 16 + col) * 516 + n) = acc[j];
  }
  __syncthreads();
#pragma unroll
  for (int i = 0; i < 4; ++i) {
    const int bi = wave * 4 + i;
    const int n0 = lane * 8;
    const float* p0 = lds + bi * 516 + n0;
    const float* p1 = lds + (16 + bi) * 516 + n0;
    f32x4 s0 = *(const f32x4*)p0 + *(const f32x4*)p1 + *(const f32x4*)(bsl + n0);
    f32x4 s1 = *(const f32x4*)(p0 + 4) + *(const f32x4*)(p1 + 4)
             + *(const f32x4*)(bsl + n0 + 4);
    bf16x8 hb;
#pragma unroll
    for (int j = 0; j < 4; ++j) { hb[j] = (bf16)s0[j]; hb[4 + j] = (bf16)s1[j]; }
    *(bf16x8*)(hg + (long)(b0 + bi) * 512 + n0) = hb;
    const float* wl = wlin + (long)tc * 512 + n0;
    f32x4 w0 = *(const f32x4*)wl, w1 = *(const f32x4*)(wl + 4);
    float dot = s0[0]*w0[0] + s0[1]*w0[1] + s0[2]*w0[2] + s0[3]*w0[3]
              + s1[0]*w1[0] + s1[1]*w1[1] + s1[2]*w1[2] + s1[3]*w1[3];
    for (int d = 32; d > 0; d >>= 1) dot += __shfl_xor(dot, d, 64);
    if (lane == 0) out[tc * 128 + (b0 + bi)] = dot + blin[tc];
  }
}

// ------------------------- persistent pipelined kernel ---------------------
// grid 336 (= max slot work, 8 barrier-groups of 42). 2 blocks/CU capacity.
__global__ __launch_bounds__(256, 2) void k_persist(
    const bf16* __restrict__ xbf, const bf16* __restrict__ Wcat,
    const float* __restrict__ b_l, const bf16* __restrict__ Wg,
    const float* __restrict__ bg, const bf16* __restrict__ Wt,
    const float* __restrict__ bilc, const bf16* __restrict__ Wslb,
    const float* __restrict__ bsl, const float* __restrict__ Wlin,
    const float* __restrict__ blin,
    bf16* hs0, bf16* hs1, bf16* hgb, float* cs0, float* cs1,
    bf16* icat, bf16* ccat, float* t1s, float* t2s, bf16* catb,
    float* out, int* bar)
{
  __shared__ float lds[16512];   // 66KB: slg+fin accumulator exchange
  const int tid = threadIdx.x;
  for (int s = 0; s < 65; ++s) {
    const bool doL = s < 64, doC = s > 0;
    const int t = doL ? s : 63, tc = doC ? s - 1 : 0;
    const bf16*  hsR = (t & 1) ? hs1 : hs0;
    bf16*        hsW = (t & 1) ? hs0 : hs1;
    const float* csR = (t & 1) ? cs1 : cs0;
    float*       csW = (t & 1) ? cs0 : cs1;
    const bf16*  hsC = (tc & 1) ? hs0 : hs1;
    const float* csC = (tc & 1) ? cs0 : cs1;
    for (int sl = 0; sl < 5; ++sl) {
      const int nL = doL ? 96 : 0;
      const int nC = doC ? ((sl < 2) ? 240 : (sl == 2) ? 80 : (sl == 3) ? 40 : 8) : 0;
      const bf16* A0 = (sl == 0) ? xbf + (long)t * 65536
                                 : hsW + (long)(sl - 1) * 196608;
      const long a0ss = (sl == 0) ? 0L : 65536L;
      for (int vb = blockIdx.x; vb < nL + nC; vb += (int)gridDim.x) {
        if (vb < nL) {
          d_lstm(vb, tid, A0, a0ss, hsR + (long)sl * 196608,
                 Wcat + (long)sl * 2097152, b_l + sl * 2048,
                 csR + (long)sl * 196608, csW + (long)sl * 196608,
                 hsW + (long)sl * 196608);
        } else {
          const int cv = vb - nL;
          if (sl == 0)      d_cell(cv,       tid, hgb, hsC, Wg, bg, csC, icat, ccat);
          else if (sl == 1) d_cell(cv + 240, tid, hgb, hsC, Wg, bg, csC, icat, ccat);
          else if (sl == 2) d_tg  (cv, tid, icat, ccat, Wt, bilc, t1s, t2s);
          else if (sl == 3) d_comb(cv, tid, t1s, t2s, catb);
          else d_slgfin(cv, tid, catb, Wslb, bsl, Wlin, blin, hgb, out, tc, lds);
        }
      }
      gsync(bar, 336);
    }
  }
}

// ------------------------- weight conversion kernels -----------------------
__global__ __launch_bounds__(256) void cvt_wxh(const float* __restrict__ Wx,
    const float* __restrict__ Wh, bf16* __restrict__ dst)
{
  long idx = ((long)blockIdx.x * 256 + threadIdx.x) * 4;   // [al][n][k], n=4o+g
  int k = (int)(idx & 1023);
  int n = (int)((idx >> 10) & 2047);
  long al = idx >> 21;                                     // a*5+l
  int g = n & 3, o = n >> 2;
  const float* src = (k < 512)
      ? Wx + ((al * 4 + g) * 512 + o) * 512 + k
      : Wh + ((al * 4 + g) * 512 + o) * 512 + (k - 512);
  f32x4 v = *(const f32x4*)src;
  bf16x4 ov;
#pragma unroll
  for (int j = 0; j < 4; ++j) ov[j] = (bf16)v[j];
  *(bf16x4*)(dst + idx) = ov;
}

__global__ __launch_bounds__(256) void cvt_wg(const float* __restrict__ Wg_h,
    const float* __restrict__ Wg_p, bf16* __restrict__ dst)
{
  long idx = ((long)blockIdx.x * 256 + threadIdx.x) * 4;   // [la][n=4z+g][k], g==3 pad
  int k = (int)(idx & 1023);
  int n = (int)((idx >> 10) & 2047);
  long la = idx >> 21;                                     // l*3+a
  int g = n & 3, z = n >> 2;
  f32x4 v = {0, 0, 0, 0};
  if (g < 3) {
    const float* src = (k < 512)
        ? Wg_h + ((la * 3 + g) * 512 + z) * 512 + k
        : Wg_p + ((la * 3 + g) * 512 + z) * 512 + (k - 512);
    v = *(const f32x4*)src;
  }
  bf16x4 ov;
#pragma unroll
  for (int j = 0; j < 4; ++j) ov[j] = (bf16)v[j];
  *(bf16x4*)(dst + idx) = ov;
}

__global__ __launch_bounds__(256) void cvt_wt(const float* __restrict__ Wilc,
                                              bf16* __restrict__ dst)
{
  long idx = (long)blockIdx.x * 256 + threadIdx.x;         // [l][y][k=a*512+z]
  int k = (int)(idx % 1536);
  long rest = idx / 1536;
  int y = (int)(rest & 511);
  int l = (int)(rest >> 9);
  int a = k >> 9, z = k & 511;
  dst[idx] = (bf16)Wilc[(((long)l * 3 + a) * 512 + z) * 512 + y];
}

__global__ __launch_bounds__(256) void k_cast(const float* __restrict__ s,
                                              bf16* __restrict__ d)
{
  long i = ((long)blockIdx.x * 256 + threadIdx.x) * 4;
  f32x4 v = *(const f32x4*)(s + i);
  bf16x4 ov;
#pragma unroll
  for (int j = 0; j < 4; ++j) ov[j] = (bf16)v[j];
  *(bf16x4*)(d + i) = ov;
}

__global__ __launch_bounds__(256) void k_zero(uint4* __restrict__ p, long n)
{
  long i = (long)blockIdx.x * 256 + threadIdx.x;
  if (i < n) p[i] = make_uint4(0, 0, 0, 0);
}

// ---------------------------------------------------------------------------
extern "C" void kernel_launch(void* const* d_in, const int* in_sizes, int n_in,
                              void* d_out, int out_size, void* d_ws, size_t ws_size,
                              hipStream_t stream)
{
  const float* x    = (const float*)d_in[0];
  const float* Wx   = (const float*)d_in[1];
  const float* Wh   = (const float*)d_in[2];
  const float* b_l  = (const float*)d_in[3];
  const float* Wg_h = (const float*)d_in[4];
  const float* Wg_p = (const float*)d_in[5];
  const float* bg   = (const float*)d_in[6];
  const float* Wilc = (const float*)d_in[7];
  const float* bilc = (const float*)d_in[8];
  const float* Wsl  = (const float*)d_in[9];
  const float* bsl  = (const float*)d_in[10];
  const float* Wlin = (const float*)d_in[11];
  const float* blin = (const float*)d_in[12];
  float* out = (float*)d_out;

  char* w = (char*)d_ws;
  auto alloc = [&](long bytes) { char* p = w; w += (bytes + 255) & ~255L; return p; };
  bf16* Wcat = (bf16*)alloc(31457280L * 2);   // [a][l][2048][1024]
  bf16* Wg   = (bf16*)alloc(31457280L * 2);   // [l*3+a][2048][1024]
  bf16* Wt   = (bf16*)alloc(3932160L * 2);    // [l][512][1536]
  bf16* Wslb = (bf16*)alloc(1310720L * 2);    // [512][2560]
  bf16* xbf  = (bf16*)alloc(4194304L * 2);    // [t][b][512]
  char* zbase = w;
  bf16* hs0  = (bf16*)alloc(983040L * 2);     // [l][a][b][512] ping
  bf16* hs1  = (bf16*)alloc(983040L * 2);     // pong
  bf16* hgb  = (bf16*)alloc(65536L * 2);      // [b][512]
  float* cs0 = (float*)alloc(983040L * 4);    // [l][a][b][512] ping
  float* cs1 = (float*)alloc(983040L * 4);    // pong
  int*  bar  = (int*)alloc(4096);             // hierarchical barrier state
  long zbytes = w - zbase;
  bf16* icat = (bf16*)alloc(983040L * 2);     // [l][b][1536]
  bf16* ccat = (bf16*)alloc(983040L * 2);
  float* t1s = (float*)alloc(327680L * 4);    // [l][b][512]
  float* t2s = (float*)alloc(327680L * 4);
  bf16* catb = (bf16*)alloc(327680L * 2);     // [b][2560]
  (void)ws_size; (void)n_in; (void)in_sizes; (void)out_size;

  // --- setup (runs every call; ws is re-poisoned by the harness) ---
  cvt_wxh<<<30720, 256, 0, stream>>>(Wx, Wh, Wcat);
  cvt_wg <<<30720, 256, 0, stream>>>(Wg_h, Wg_p, Wg);
  cvt_wt <<<15360, 256, 0, stream>>>(Wilc, Wt);
  k_cast <<<1280,  256, 0, stream>>>(Wsl, Wslb);
  k_cast <<<4096,  256, 0, stream>>>(x, xbf);
  {
    long n16 = zbytes / 16;
    k_zero<<<(int)((n16 + 255) / 256), 256, 0, stream>>>((uint4*)zbase, n16);
  }

  // --- one persistent kernel runs the whole 64-step recurrence ---
  k_persist<<<336, 256, 0, stream>>>(
      xbf, Wcat, b_l, Wg, bg, Wt, bilc, Wslb, bsl, Wlin, blin,
      hs0, hs1, hgb, cs0, cs1, icat, ccat, t1s, t2s, catb, out, bar);
}